// Round 1
// baseline (1587.009 us; speedup 1.0000x reference)
//
#include <hip/hip_runtime.h>

// GCN 2-layer + softmax head on MI355X.
// R1 baseline: fp32 tiled GEMMs (no fp32 MFMA on CDNA4 -> vector ALU),
// edge-parallel aggregation with native fp32 global atomics.
// Factored norm: agg[d] = dis[d] * sum_{s->d} dis[s]*h[s]; dis[s] folded into
// GEMM epilogue, self-loop folded into the post (bias+relu) pass.

#define N_NODES 50000
#define N_EDGES 800000
#define N_FEAT 256
#define HIDDEN 128
#define N_CLASSES 16

__device__ __forceinline__ void atomic_add_f32(float* p, float v) {
    __hip_atomic_fetch_add(p, v, __ATOMIC_RELAXED, __HIP_MEMORY_SCOPE_AGENT);
}

__global__ void init_deg(float* __restrict__ deg, int n) {
    int i = blockIdx.x * blockDim.x + threadIdx.x;
    if (i < n) deg[i] = 1.0f;  // self-loop contributes 1
}

__global__ void count_deg(const int* __restrict__ dst, float* __restrict__ deg, int nE) {
    int e = blockIdx.x * blockDim.x + threadIdx.x;
    if (e < nE) atomic_add_f32(&deg[dst[e]], 1.0f);
}

__global__ void rsqrt_inplace(float* __restrict__ deg, int n) {
    int i = blockIdx.x * blockDim.x + threadIdx.x;
    if (i < n) deg[i] = rsqrtf(deg[i]);  // deg >= 1 always (self-loop)
}

// C[M x N] = (A[M x K] @ W[K x N]) * dis[row]   (row-scaled epilogue)
// BM=64, BN=N(=128), BK=32, 256 threads, each thread 4x8 outputs.
template <int K, int N>
__global__ __launch_bounds__(256) void gemm_scale(
    const float* __restrict__ A, const float* __restrict__ W,
    const float* __restrict__ dis, float* __restrict__ out, int M)
{
    constexpr int BM = 64, BK = 32;
    __shared__ float a_lds[BK][BM + 1];  // transposed A-tile, +1 pad (scalar reads)
    __shared__ float b_lds[BK][N];

    const int tid = threadIdx.x;
    const int tx = tid & 15;   // 16 column groups of 8
    const int ty = tid >> 4;   // 16 row groups of 4
    const int row0 = blockIdx.x * BM;

    float acc[4][8] = {};

    for (int k0 = 0; k0 < K; k0 += BK) {
        // A tile 64x32 -> transposed LDS. 512 float4 loads, 2/thread.
#pragma unroll
        for (int p = 0; p < 2; ++p) {
            int idx = tid + p * 256;        // 0..511 float4 index
            int r   = idx >> 3;             // 0..63
            int c4  = (idx & 7) * 4;        // 0,4,...,28
            int gr  = row0 + r;
            float4 v = make_float4(0.f, 0.f, 0.f, 0.f);
            if (gr < M) v = *(const float4*)(A + (size_t)gr * K + k0 + c4);
            a_lds[c4 + 0][r] = v.x;
            a_lds[c4 + 1][r] = v.y;
            a_lds[c4 + 2][r] = v.z;
            a_lds[c4 + 3][r] = v.w;
        }
        // B tile 32xN. (32*N/4) float4, (32*N)/(1024) per thread.
#pragma unroll
        for (int p = 0; p < (BK * N) / (256 * 4); ++p) {
            int idx = tid + p * 256;
            int r   = idx / (N / 4);
            int c4  = (idx % (N / 4)) * 4;
            *(float4*)(&b_lds[r][c4]) = *(const float4*)(W + (size_t)(k0 + r) * N + c4);
        }
        __syncthreads();

#pragma unroll
        for (int kk = 0; kk < BK; ++kk) {
            float a[4];
#pragma unroll
            for (int i = 0; i < 4; ++i) a[i] = a_lds[kk][ty * 4 + i];
            float4 b0 = *(const float4*)(&b_lds[kk][tx * 8]);
            float4 b1 = *(const float4*)(&b_lds[kk][tx * 8 + 4]);
            float b[8] = {b0.x, b0.y, b0.z, b0.w, b1.x, b1.y, b1.z, b1.w};
#pragma unroll
            for (int i = 0; i < 4; ++i)
#pragma unroll
                for (int j = 0; j < 8; ++j)
                    acc[i][j] += a[i] * b[j];
        }
        __syncthreads();
    }

#pragma unroll
    for (int i = 0; i < 4; ++i) {
        int gr = row0 + ty * 4 + i;
        if (gr < M) {
            float s = dis[gr];
            float4 o0 = make_float4(acc[i][0] * s, acc[i][1] * s, acc[i][2] * s, acc[i][3] * s);
            float4 o1 = make_float4(acc[i][4] * s, acc[i][5] * s, acc[i][6] * s, acc[i][7] * s);
            *(float4*)(out + (size_t)gr * N + tx * 8)     = o0;
            *(float4*)(out + (size_t)gr * N + tx * 8 + 4) = o1;
        }
    }
}

// One wave per edge (grid-stride): agg[dst] += g[src]  (128 floats, float2/lane)
__global__ void aggregate(const float* __restrict__ g, const int* __restrict__ src,
                          const int* __restrict__ dst, float* __restrict__ agg, int nE)
{
    int gid  = blockIdx.x * blockDim.x + threadIdx.x;
    int lane = threadIdx.x & 63;
    int wid  = gid >> 6;
    int nw   = (gridDim.x * blockDim.x) >> 6;
    for (int e = wid; e < nE; e += nw) {
        int s = src[e], d = dst[e];
        float2 v = *(const float2*)(g + (size_t)s * HIDDEN + lane * 2);
        float* o = agg + (size_t)d * HIDDEN + lane * 2;
        atomic_add_f32(o + 0, v.x);
        atomic_add_f32(o + 1, v.y);
    }
}

// out = relu(dis[node]*(agg + g) + b)   in-place into agg.
// (agg holds sum over real edges; + g[node] adds the self-loop term since
//  g = dis*h and the final dis[node]* gives dis^2*h.)
__global__ void post_relu(float* __restrict__ agg, const float* __restrict__ g,
                          const float* __restrict__ dis, const float* __restrict__ b, int M)
{
    int i4 = blockIdx.x * blockDim.x + threadIdx.x;   // float4 index
    if (i4 >= M * (HIDDEN / 4)) return;
    int node = i4 >> 5;            // 32 float4 per node
    int f4   = (i4 & 31) * 4;
    float s = dis[node];
    float4 av = *(float4*)((float*)agg + (size_t)i4 * 4);
    float4 gv = *(const float4*)(g + (size_t)i4 * 4);
    float4 bv = *(const float4*)(b + f4);
    float4 o;
    o.x = fmaxf(s * (av.x + gv.x) + bv.x, 0.f);
    o.y = fmaxf(s * (av.y + gv.y) + bv.y, 0.f);
    o.z = fmaxf(s * (av.z + gv.z) + bv.z, 0.f);
    o.w = fmaxf(s * (av.w + gv.w) + bv.w, 0.f);
    *(float4*)((float*)agg + (size_t)i4 * 4) = o;
}

// softmax(h @ Wout + bout) ; one thread per node, Wout staged in LDS (8KB).
__global__ void head_softmax(const float* __restrict__ h, const float* __restrict__ Wout,
                             const float* __restrict__ bout, float* __restrict__ out, int M)
{
    __shared__ float w[HIDDEN * N_CLASSES];
    for (int i = threadIdx.x; i < HIDDEN * N_CLASSES; i += blockDim.x) w[i] = Wout[i];
    __syncthreads();

    int node = blockIdx.x * blockDim.x + threadIdx.x;
    if (node >= M) return;

    const float4* hp = (const float4*)(h + (size_t)node * HIDDEN);
    float acc[N_CLASSES];
#pragma unroll
    for (int c = 0; c < N_CLASSES; ++c) acc[c] = bout[c];
#pragma unroll
    for (int k4 = 0; k4 < HIDDEN / 4; ++k4) {
        float4 hv = hp[k4];
#pragma unroll
        for (int c = 0; c < N_CLASSES; ++c) {
            acc[c] += hv.x * w[(k4 * 4 + 0) * N_CLASSES + c]
                    + hv.y * w[(k4 * 4 + 1) * N_CLASSES + c]
                    + hv.z * w[(k4 * 4 + 2) * N_CLASSES + c]
                    + hv.w * w[(k4 * 4 + 3) * N_CLASSES + c];
        }
    }
    float m = acc[0];
#pragma unroll
    for (int c = 1; c < N_CLASSES; ++c) m = fmaxf(m, acc[c]);
    float sum = 0.f;
#pragma unroll
    for (int c = 0; c < N_CLASSES; ++c) { acc[c] = expf(acc[c] - m); sum += acc[c]; }
    float inv = 1.0f / sum;
#pragma unroll
    for (int c4 = 0; c4 < N_CLASSES; c4 += 4) {
        float4 o = make_float4(acc[c4] * inv, acc[c4 + 1] * inv, acc[c4 + 2] * inv, acc[c4 + 3] * inv);
        *(float4*)(out + (size_t)node * N_CLASSES + c4) = o;
    }
}

extern "C" void kernel_launch(void* const* d_in, const int* in_sizes, int n_in,
                              void* d_out, int out_size, void* d_ws, size_t ws_size,
                              hipStream_t stream)
{
    const float* x    = (const float*)d_in[0];
    const int*   ei   = (const int*)d_in[1];   // [2, N_EDGES]; row0=src, row1=dst (int32 assumed)
    const float* W1   = (const float*)d_in[2];
    const float* b1   = (const float*)d_in[3];
    const float* W2   = (const float*)d_in[4];
    const float* b2   = (const float*)d_in[5];
    const float* Wout = (const float*)d_in[6];
    const float* bout = (const float*)d_in[7];
    float* out = (float*)d_out;

    const int* src = ei;
    const int* dst = ei + N_EDGES;

    // Workspace: dis (50176 f, 256B-aligned pad) | A (6.4M f) | B (6.4M f) ~= 51.4 MB
    float* dis = (float*)d_ws;
    float* A   = dis + 50176;
    float* B   = A + (size_t)N_NODES * HIDDEN;

    const size_t featBytes = (size_t)N_NODES * HIDDEN * sizeof(float);

    init_deg<<<(N_NODES + 255) / 256, 256, 0, stream>>>(dis, N_NODES);
    count_deg<<<(N_EDGES + 255) / 256, 256, 0, stream>>>(dst, dis, N_EDGES);
    rsqrt_inplace<<<(N_NODES + 255) / 256, 256, 0, stream>>>(dis, N_NODES);

    // Layer 1: A = (x@W1)*dis ; B = scatter(A) ; B = relu(dis*(B+A)+b1)
    gemm_scale<N_FEAT, HIDDEN><<<(N_NODES + 63) / 64, 256, 0, stream>>>(x, W1, dis, A, N_NODES);
    hipMemsetAsync(B, 0, featBytes, stream);
    aggregate<<<2048, 256, 0, stream>>>(A, src, dst, B, N_EDGES);
    post_relu<<<(N_NODES * (HIDDEN / 4) + 255) / 256, 256, 0, stream>>>(B, A, dis, b1, N_NODES);

    // Layer 2: A = (B@W2)*dis ; B = scatter(A) ; B = relu(dis*(B+A)+b2)
    gemm_scale<HIDDEN, HIDDEN><<<(N_NODES + 63) / 64, 256, 0, stream>>>(B, W2, dis, A, N_NODES);
    hipMemsetAsync(B, 0, featBytes, stream);
    aggregate<<<2048, 256, 0, stream>>>(A, src, dst, B, N_EDGES);
    post_relu<<<(N_NODES * (HIDDEN / 4) + 255) / 256, 256, 0, stream>>>(B, A, dis, b2, N_NODES);

    // Head: softmax(B @ Wout + bout)
    head_softmax<<<(N_NODES + 255) / 256, 256, 0, stream>>>(B, Wout, bout, out, N_NODES);
}

// Round 2
// 520.097 us; speedup vs baseline: 3.0514x; 3.0514x over previous
//
#include <hip/hip_runtime.h>

// GCN 2-layer + softmax head on MI355X.
// R2: CSR-based gather aggregation (no fp32 atomics), fused self-loop+bias+relu
// epilogue. fp32 tiled GEMMs unchanged (next target).
// Factored norm: out[d] = relu(dis[d] * (sum_{s->d} g[s] + g[d]) + b),
// where g = (h @ W) * dis  (dis[s] folded into GEMM epilogue).

#define N_NODES 50000
#define N_EDGES 800000
#define N_FEAT 256
#define HIDDEN 128
#define N_CLASSES 16

__device__ __forceinline__ void atomic_add_f32(float* p, float v) {
    __hip_atomic_fetch_add(p, v, __ATOMIC_RELAXED, __HIP_MEMORY_SCOPE_AGENT);
}
__device__ __forceinline__ int atomic_add_i32(int* p, int v) {
    return __hip_atomic_fetch_add(p, v, __ATOMIC_RELAXED, __HIP_MEMORY_SCOPE_AGENT);
}

// ---- CSR build ----------------------------------------------------------

__global__ void count_deg(const int* __restrict__ dst, int* __restrict__ cnt, int nE) {
    int e = blockIdx.x * blockDim.x + threadIdx.x;
    if (e < nE) atomic_add_i32(&cnt[dst[e]], 1);
}

// Single block, 1024 threads: exclusive scan of cnt -> row_off (n+1), cursor
// copy, and dis = rsqrt(cnt+1) (self-loop included in degree).
__global__ __launch_bounds__(1024) void scan_build(
    const int* __restrict__ cnt, int* __restrict__ row_off, int* __restrict__ cursor,
    float* __restrict__ dis, int n)
{
    __shared__ int part[1024];
    const int tid = threadIdx.x;
    const int C = (n + 1023) / 1024;           // 49
    const int beg = tid * C, end = min(n, beg + C);

    int s = 0;
    for (int i = beg; i < end; ++i) s += cnt[i];
    part[tid] = s;
    __syncthreads();
    // Hillis-Steele inclusive scan over 1024 partials
    for (int off = 1; off < 1024; off <<= 1) {
        int v = (tid >= off) ? part[tid - off] : 0;
        __syncthreads();
        part[tid] += v;
        __syncthreads();
    }
    int running = (tid == 0) ? 0 : part[tid - 1];   // exclusive
    for (int i = beg; i < end; ++i) {
        row_off[i] = running;
        cursor[i]  = running;
        dis[i]     = rsqrtf((float)(cnt[i] + 1));
        running += cnt[i];
    }
    if (tid == 1023) row_off[n] = running;
}

__global__ void scatter_edges(const int* __restrict__ src, const int* __restrict__ dst,
                              int* __restrict__ cursor, int* __restrict__ esrc, int nE)
{
    int e = blockIdx.x * blockDim.x + threadIdx.x;
    if (e < nE) {
        int pos = atomic_add_i32(&cursor[dst[e]], 1);
        esrc[pos] = src[e];
    }
}

// ---- GEMM with row-scale epilogue --------------------------------------
// C[M x N] = (A[M x K] @ W[K x N]) * dis[row]
// BM=64, BN=N(=128), BK=32, 256 threads, each thread 4x8 outputs.
template <int K, int N>
__global__ __launch_bounds__(256) void gemm_scale(
    const float* __restrict__ A, const float* __restrict__ W,
    const float* __restrict__ dis, float* __restrict__ out, int M)
{
    constexpr int BM = 64, BK = 32;
    __shared__ float a_lds[BK][BM + 1];
    __shared__ float b_lds[BK][N];

    const int tid = threadIdx.x;
    const int tx = tid & 15;
    const int ty = tid >> 4;
    const int row0 = blockIdx.x * BM;

    float acc[4][8] = {};

    for (int k0 = 0; k0 < K; k0 += BK) {
#pragma unroll
        for (int p = 0; p < 2; ++p) {
            int idx = tid + p * 256;
            int r   = idx >> 3;
            int c4  = (idx & 7) * 4;
            int gr  = row0 + r;
            float4 v = make_float4(0.f, 0.f, 0.f, 0.f);
            if (gr < M) v = *(const float4*)(A + (size_t)gr * K + k0 + c4);
            a_lds[c4 + 0][r] = v.x;
            a_lds[c4 + 1][r] = v.y;
            a_lds[c4 + 2][r] = v.z;
            a_lds[c4 + 3][r] = v.w;
        }
#pragma unroll
        for (int p = 0; p < (BK * N) / (256 * 4); ++p) {
            int idx = tid + p * 256;
            int r   = idx / (N / 4);
            int c4  = (idx % (N / 4)) * 4;
            *(float4*)(&b_lds[r][c4]) = *(const float4*)(W + (size_t)(k0 + r) * N + c4);
        }
        __syncthreads();

#pragma unroll
        for (int kk = 0; kk < BK; ++kk) {
            float a[4];
#pragma unroll
            for (int i = 0; i < 4; ++i) a[i] = a_lds[kk][ty * 4 + i];
            float4 b0 = *(const float4*)(&b_lds[kk][tx * 8]);
            float4 b1 = *(const float4*)(&b_lds[kk][tx * 8 + 4]);
            float b[8] = {b0.x, b0.y, b0.z, b0.w, b1.x, b1.y, b1.z, b1.w};
#pragma unroll
            for (int i = 0; i < 4; ++i)
#pragma unroll
                for (int j = 0; j < 8; ++j)
                    acc[i][j] += a[i] * b[j];
        }
        __syncthreads();
    }

#pragma unroll
    for (int i = 0; i < 4; ++i) {
        int gr = row0 + ty * 4 + i;
        if (gr < M) {
            float s = dis[gr];
            float4 o0 = make_float4(acc[i][0] * s, acc[i][1] * s, acc[i][2] * s, acc[i][3] * s);
            float4 o1 = make_float4(acc[i][4] * s, acc[i][5] * s, acc[i][6] * s, acc[i][7] * s);
            *(float4*)(out + (size_t)gr * N + tx * 8)     = o0;
            *(float4*)(out + (size_t)gr * N + tx * 8 + 4) = o1;
        }
    }
}

// ---- CSR aggregation, fused epilogue -----------------------------------
// One wave per destination node. lane holds float2 of the 128-wide feature.
// out[d] = relu(dis[d] * (g[d] + sum_{e} g[esrc[e]]) + bias)
__global__ __launch_bounds__(256) void aggregate_csr(
    const float* __restrict__ g, const int* __restrict__ row_off,
    const int* __restrict__ esrc, const float* __restrict__ dis,
    const float* __restrict__ bias, float* __restrict__ out, int M)
{
    const int wid  = (blockIdx.x * blockDim.x + threadIdx.x) >> 6;
    const int lane = threadIdx.x & 63;
    if (wid >= M) return;

    const int beg = row_off[wid];
    const int end = row_off[wid + 1];

    // self-loop term
    float2 sum = *(const float2*)(g + (size_t)wid * HIDDEN + lane * 2);

    for (int e0 = beg; e0 < end; e0 += 64) {
        const int cnt = min(64, end - e0);
        int myidx = (lane < cnt) ? esrc[e0 + lane] : 0;
        int j = 0;
        for (; j + 3 < cnt; j += 4) {
            int s0 = __shfl(myidx, j);
            int s1 = __shfl(myidx, j + 1);
            int s2 = __shfl(myidx, j + 2);
            int s3 = __shfl(myidx, j + 3);
            float2 v0 = *(const float2*)(g + (size_t)s0 * HIDDEN + lane * 2);
            float2 v1 = *(const float2*)(g + (size_t)s1 * HIDDEN + lane * 2);
            float2 v2 = *(const float2*)(g + (size_t)s2 * HIDDEN + lane * 2);
            float2 v3 = *(const float2*)(g + (size_t)s3 * HIDDEN + lane * 2);
            sum.x += v0.x + v1.x + v2.x + v3.x;
            sum.y += v0.y + v1.y + v2.y + v3.y;
        }
        for (; j < cnt; ++j) {
            int s = __shfl(myidx, j);
            float2 v = *(const float2*)(g + (size_t)s * HIDDEN + lane * 2);
            sum.x += v.x;
            sum.y += v.y;
        }
    }

    const float sc = dis[wid];
    float2 bv = *(const float2*)(bias + lane * 2);
    float2 o;
    o.x = fmaxf(sc * sum.x + bv.x, 0.f);
    o.y = fmaxf(sc * sum.y + bv.y, 0.f);
    *(float2*)(out + (size_t)wid * HIDDEN + lane * 2) = o;
}

// ---- head ---------------------------------------------------------------
__global__ void head_softmax(const float* __restrict__ h, const float* __restrict__ Wout,
                             const float* __restrict__ bout, float* __restrict__ out, int M)
{
    __shared__ float w[HIDDEN * N_CLASSES];
    for (int i = threadIdx.x; i < HIDDEN * N_CLASSES; i += blockDim.x) w[i] = Wout[i];
    __syncthreads();

    int node = blockIdx.x * blockDim.x + threadIdx.x;
    if (node >= M) return;

    const float4* hp = (const float4*)(h + (size_t)node * HIDDEN);
    float acc[N_CLASSES];
#pragma unroll
    for (int c = 0; c < N_CLASSES; ++c) acc[c] = bout[c];
#pragma unroll
    for (int k4 = 0; k4 < HIDDEN / 4; ++k4) {
        float4 hv = hp[k4];
#pragma unroll
        for (int c = 0; c < N_CLASSES; ++c) {
            acc[c] += hv.x * w[(k4 * 4 + 0) * N_CLASSES + c]
                    + hv.y * w[(k4 * 4 + 1) * N_CLASSES + c]
                    + hv.z * w[(k4 * 4 + 2) * N_CLASSES + c]
                    + hv.w * w[(k4 * 4 + 3) * N_CLASSES + c];
        }
    }
    float m = acc[0];
#pragma unroll
    for (int c = 1; c < N_CLASSES; ++c) m = fmaxf(m, acc[c]);
    float sum = 0.f;
#pragma unroll
    for (int c = 0; c < N_CLASSES; ++c) { acc[c] = expf(acc[c] - m); sum += acc[c]; }
    float inv = 1.0f / sum;
#pragma unroll
    for (int c4 = 0; c4 < N_CLASSES; c4 += 4) {
        float4 o = make_float4(acc[c4] * inv, acc[c4 + 1] * inv, acc[c4 + 2] * inv, acc[c4 + 3] * inv);
        *(float4*)(out + (size_t)node * N_CLASSES + c4) = o;
    }
}

// ---- launch -------------------------------------------------------------
extern "C" void kernel_launch(void* const* d_in, const int* in_sizes, int n_in,
                              void* d_out, int out_size, void* d_ws, size_t ws_size,
                              hipStream_t stream)
{
    const float* x    = (const float*)d_in[0];
    const int*   ei   = (const int*)d_in[1];   // [2, N_EDGES]; row0=src, row1=dst
    const float* W1   = (const float*)d_in[2];
    const float* b1   = (const float*)d_in[3];
    const float* W2   = (const float*)d_in[4];
    const float* b2   = (const float*)d_in[5];
    const float* Wout = (const float*)d_in[6];
    const float* bout = (const float*)d_in[7];
    float* out = (float*)d_out;

    const int* src = ei;
    const int* dst = ei + N_EDGES;

    // Workspace layout (4B units):
    float* dis    = (float*)d_ws;            // 50176
    int*   cnt    = (int*)(dis + 50176);     // 50176
    int*   row_off= cnt + 50176;             // 50432 (n+1, padded)
    int*   cursor = row_off + 50432;         // 50176
    int*   esrc   = cursor + 50176;          // 800000
    float* A      = (float*)(esrc + 800000); // 6.4M
    float* B      = A + (size_t)N_NODES * HIDDEN;

    // CSR build
    hipMemsetAsync(cnt, 0, 50176 * sizeof(int), stream);
    count_deg<<<(N_EDGES + 255) / 256, 256, 0, stream>>>(dst, cnt, N_EDGES);
    scan_build<<<1, 1024, 0, stream>>>(cnt, row_off, cursor, dis, N_NODES);
    scatter_edges<<<(N_EDGES + 255) / 256, 256, 0, stream>>>(src, dst, cursor, esrc, N_EDGES);

    const int aggGrid = (N_NODES * 64 + 255) / 256;   // one wave per node

    // Layer 1
    gemm_scale<N_FEAT, HIDDEN><<<(N_NODES + 63) / 64, 256, 0, stream>>>(x, W1, dis, A, N_NODES);
    aggregate_csr<<<aggGrid, 256, 0, stream>>>(A, row_off, esrc, dis, b1, B, N_NODES);

    // Layer 2
    gemm_scale<HIDDEN, HIDDEN><<<(N_NODES + 63) / 64, 256, 0, stream>>>(B, W2, dis, A, N_NODES);
    aggregate_csr<<<aggGrid, 256, 0, stream>>>(A, row_off, esrc, dis, b2, B, N_NODES);

    // Head
    head_softmax<<<(N_NODES + 255) / 256, 256, 0, stream>>>(B, Wout, bout, out, N_NODES);
}

// Round 6
// 397.104 us; speedup vs baseline: 3.9965x; 1.3097x over previous
//
#include <hip/hip_runtime.h>

// GCN 2-layer + softmax head on MI355X.
// R3 (third resubmit; three consecutive GPU-acquisition timeouts — this
// source has never executed on hardware):
// (a) parallel 3-kernel CSR scan (R2's single-block scan was 134us,
// 0.14% occupancy); (b) fp32 GEMM upgraded to 128x128 tile, 8x8 microtile
// (FMA:LDS ratio 64:4 per k-step). Aggregation unchanged.

#define N_NODES 50000
#define N_EDGES 800000
#define N_FEAT 256
#define HIDDEN 128
#define N_CLASSES 16

#define SCAN_BLK 256
#define N_SCAN_BLKS ((N_NODES + SCAN_BLK - 1) / SCAN_BLK)   // 196

__device__ __forceinline__ int atomic_add_i32(int* p, int v) {
    return __hip_atomic_fetch_add(p, v, __ATOMIC_RELAXED, __HIP_MEMORY_SCOPE_AGENT);
}

// ---- CSR build ----------------------------------------------------------

__global__ void count_deg(const int* __restrict__ dst, int* __restrict__ cnt, int nE) {
    int e = blockIdx.x * blockDim.x + threadIdx.x;
    if (e < nE) atomic_add_i32(&cnt[dst[e]], 1);
}

// per-block sums of cnt
__global__ __launch_bounds__(SCAN_BLK) void scan_p1(const int* __restrict__ cnt,
                                                    int* __restrict__ bsum, int n) {
    __shared__ int red[SCAN_BLK];
    int tid = threadIdx.x;
    int i = blockIdx.x * SCAN_BLK + tid;
    red[tid] = (i < n) ? cnt[i] : 0;
    __syncthreads();
    for (int off = SCAN_BLK / 2; off > 0; off >>= 1) {
        if (tid < off) red[tid] += red[tid + off];
        __syncthreads();
    }
    if (tid == 0) bsum[blockIdx.x] = red[0];
}

// single small block: exclusive scan of the 196 block sums
__global__ __launch_bounds__(SCAN_BLK) void scan_p2(const int* __restrict__ bsum,
                                                    int* __restrict__ boff, int nb) {
    __shared__ int s[SCAN_BLK];
    int tid = threadIdx.x;
    int v = (tid < nb) ? bsum[tid] : 0;
    s[tid] = v;
    __syncthreads();
    for (int off = 1; off < SCAN_BLK; off <<= 1) {
        int t = (tid >= off) ? s[tid - off] : 0;
        __syncthreads();
        s[tid] += t;
        __syncthreads();
    }
    boff[tid] = s[tid] - v;   // exclusive
}

// local scan + block offset -> row_off/cursor/dis
__global__ __launch_bounds__(SCAN_BLK) void scan_p3(
    const int* __restrict__ cnt, const int* __restrict__ boff,
    int* __restrict__ row_off, int* __restrict__ cursor,
    float* __restrict__ dis, int n)
{
    __shared__ int s[SCAN_BLK];
    int tid = threadIdx.x;
    int i = blockIdx.x * SCAN_BLK + tid;
    int v = (i < n) ? cnt[i] : 0;
    s[tid] = v;
    __syncthreads();
    for (int off = 1; off < SCAN_BLK; off <<= 1) {
        int t = (tid >= off) ? s[tid - off] : 0;
        __syncthreads();
        s[tid] += t;
        __syncthreads();
    }
    int excl = boff[blockIdx.x] + s[tid] - v;
    if (i < n) {
        row_off[i] = excl;
        cursor[i]  = excl;
        dis[i]     = rsqrtf((float)(v + 1));   // +1 self-loop
    }
    if (blockIdx.x == 0 && tid == 0) row_off[n] = N_EDGES;
}

__global__ void scatter_edges(const int* __restrict__ src, const int* __restrict__ dst,
                              int* __restrict__ cursor, int* __restrict__ esrc, int nE)
{
    int e = blockIdx.x * blockDim.x + threadIdx.x;
    if (e < nE) {
        int pos = atomic_add_i32(&cursor[dst[e]], 1);
        esrc[pos] = src[e];
    }
}

// ---- GEMM with row-scale epilogue --------------------------------------
// C[M x 128] = (A[M x K] @ W[K x 128]) * dis[row]
// BM=128, BN=128, BK=16, 256 threads, 8x8 outputs/thread.
template <int K>
__global__ __launch_bounds__(256) void gemm_scale(
    const float* __restrict__ A, const float* __restrict__ W,
    const float* __restrict__ dis, float* __restrict__ out, int M)
{
    constexpr int BM = 128, BN = 128, BK = 16;
    __shared__ float a_lds[BK][BM + 4];   // transposed A-tile
    __shared__ float b_lds[BK][BN];

    const int tid = threadIdx.x;
    const int tx = tid & 15;     // column group (8 cols)
    const int ty = tid >> 4;     // row group (8 rows)
    const int row0 = blockIdx.x * BM;

    float acc[8][8] = {};

    for (int k0 = 0; k0 < K; k0 += BK) {
        // A tile: 128 rows x 16 cols = 512 float4, 2/thread, transposed store
#pragma unroll
        for (int p = 0; p < 2; ++p) {
            int idx = tid + p * 256;      // 0..511
            int r   = idx >> 2;           // 0..127
            int c4  = (idx & 3) * 4;      // 0,4,8,12
            int gr  = row0 + r;
            float4 v = make_float4(0.f, 0.f, 0.f, 0.f);
            if (gr < M) v = *(const float4*)(A + (size_t)gr * K + k0 + c4);
            a_lds[c4 + 0][r] = v.x;
            a_lds[c4 + 1][r] = v.y;
            a_lds[c4 + 2][r] = v.z;
            a_lds[c4 + 3][r] = v.w;
        }
        // B tile: 16 x 128 = 512 float4, 2/thread
#pragma unroll
        for (int p = 0; p < 2; ++p) {
            int idx = tid + p * 256;
            int r   = idx >> 5;           // 0..15
            int c4  = (idx & 31) * 4;     // 0..124
            *(float4*)(&b_lds[r][c4]) = *(const float4*)(W + (size_t)(k0 + r) * BN + c4);
        }
        __syncthreads();

#pragma unroll
        for (int kk = 0; kk < BK; ++kk) {
            float a[8], b[8];
            *(float4*)(a)     = *(const float4*)(&a_lds[kk][ty * 8]);
            *(float4*)(a + 4) = *(const float4*)(&a_lds[kk][ty * 8 + 4]);
            *(float4*)(b)     = *(const float4*)(&b_lds[kk][tx * 8]);
            *(float4*)(b + 4) = *(const float4*)(&b_lds[kk][tx * 8 + 4]);
#pragma unroll
            for (int i = 0; i < 8; ++i)
#pragma unroll
                for (int j = 0; j < 8; ++j)
                    acc[i][j] += a[i] * b[j];
        }
        __syncthreads();
    }

#pragma unroll
    for (int i = 0; i < 8; ++i) {
        int gr = row0 + ty * 8 + i;
        if (gr < M) {
            float s = dis[gr];
            float4 o0 = make_float4(acc[i][0] * s, acc[i][1] * s, acc[i][2] * s, acc[i][3] * s);
            float4 o1 = make_float4(acc[i][4] * s, acc[i][5] * s, acc[i][6] * s, acc[i][7] * s);
            *(float4*)(out + (size_t)gr * BN + tx * 8)     = o0;
            *(float4*)(out + (size_t)gr * BN + tx * 8 + 4) = o1;
        }
    }
}

// ---- CSR aggregation, fused epilogue -----------------------------------
// One wave per destination node; lane holds float2 of the 128-wide feature.
// out[d] = relu(dis[d] * (g[d] + sum_e g[esrc[e]]) + bias)
__global__ __launch_bounds__(256) void aggregate_csr(
    const float* __restrict__ g, const int* __restrict__ row_off,
    const int* __restrict__ esrc, const float* __restrict__ dis,
    const float* __restrict__ bias, float* __restrict__ out, int M)
{
    const int wid  = (blockIdx.x * blockDim.x + threadIdx.x) >> 6;
    const int lane = threadIdx.x & 63;
    if (wid >= M) return;

    const int beg = row_off[wid];
    const int end = row_off[wid + 1];

    float2 sum = *(const float2*)(g + (size_t)wid * HIDDEN + lane * 2);  // self-loop

    for (int e0 = beg; e0 < end; e0 += 64) {
        const int cnt = min(64, end - e0);
        int myidx = (lane < cnt) ? esrc[e0 + lane] : 0;
        int j = 0;
        for (; j + 3 < cnt; j += 4) {
            int s0 = __shfl(myidx, j);
            int s1 = __shfl(myidx, j + 1);
            int s2 = __shfl(myidx, j + 2);
            int s3 = __shfl(myidx, j + 3);
            float2 v0 = *(const float2*)(g + (size_t)s0 * HIDDEN + lane * 2);
            float2 v1 = *(const float2*)(g + (size_t)s1 * HIDDEN + lane * 2);
            float2 v2 = *(const float2*)(g + (size_t)s2 * HIDDEN + lane * 2);
            float2 v3 = *(const float2*)(g + (size_t)s3 * HIDDEN + lane * 2);
            sum.x += v0.x + v1.x + v2.x + v3.x;
            sum.y += v0.y + v1.y + v2.y + v3.y;
        }
        for (; j < cnt; ++j) {
            int s = __shfl(myidx, j);
            float2 v = *(const float2*)(g + (size_t)s * HIDDEN + lane * 2);
            sum.x += v.x;
            sum.y += v.y;
        }
    }

    const float sc = dis[wid];
    float2 bv = *(const float2*)(bias + lane * 2);
    float2 o;
    o.x = fmaxf(sc * sum.x + bv.x, 0.f);
    o.y = fmaxf(sc * sum.y + bv.y, 0.f);
    *(float2*)(out + (size_t)wid * HIDDEN + lane * 2) = o;
}

// ---- head ---------------------------------------------------------------
__global__ void head_softmax(const float* __restrict__ h, const float* __restrict__ Wout,
                             const float* __restrict__ bout, float* __restrict__ out, int M)
{
    __shared__ float w[HIDDEN * N_CLASSES];
    for (int i = threadIdx.x; i < HIDDEN * N_CLASSES; i += blockDim.x) w[i] = Wout[i];
    __syncthreads();

    int node = blockIdx.x * blockDim.x + threadIdx.x;
    if (node >= M) return;

    const float4* hp = (const float4*)(h + (size_t)node * HIDDEN);
    float acc[N_CLASSES];
#pragma unroll
    for (int c = 0; c < N_CLASSES; ++c) acc[c] = bout[c];
#pragma unroll
    for (int k4 = 0; k4 < HIDDEN / 4; ++k4) {
        float4 hv = hp[k4];
#pragma unroll
        for (int c = 0; c < N_CLASSES; ++c) {
            acc[c] += hv.x * w[(k4 * 4 + 0) * N_CLASSES + c]
                    + hv.y * w[(k4 * 4 + 1) * N_CLASSES + c]
                    + hv.z * w[(k4 * 4 + 2) * N_CLASSES + c]
                    + hv.w * w[(k4 * 4 + 3) * N_CLASSES + c];
        }
    }
    float m = acc[0];
#pragma unroll
    for (int c = 1; c < N_CLASSES; ++c) m = fmaxf(m, acc[c]);
    float sum = 0.f;
#pragma unroll
    for (int c = 0; c < N_CLASSES; ++c) { acc[c] = expf(acc[c] - m); sum += acc[c]; }
    float inv = 1.0f / sum;
#pragma unroll
    for (int c4 = 0; c4 < N_CLASSES; c4 += 4) {
        float4 o = make_float4(acc[c4] * inv, acc[c4 + 1] * inv, acc[c4 + 2] * inv, acc[c4 + 3] * inv);
        *(float4*)(out + (size_t)node * N_CLASSES + c4) = o;
    }
}

// ---- launch -------------------------------------------------------------
extern "C" void kernel_launch(void* const* d_in, const int* in_sizes, int n_in,
                              void* d_out, int out_size, void* d_ws, size_t ws_size,
                              hipStream_t stream)
{
    const float* x    = (const float*)d_in[0];
    const int*   ei   = (const int*)d_in[1];   // [2, N_EDGES]; row0=src, row1=dst
    const float* W1   = (const float*)d_in[2];
    const float* b1   = (const float*)d_in[3];
    const float* W2   = (const float*)d_in[4];
    const float* b2   = (const float*)d_in[5];
    const float* Wout = (const float*)d_in[6];
    const float* bout = (const float*)d_in[7];
    float* out = (float*)d_out;

    const int* src = ei;
    const int* dst = ei + N_EDGES;

    // Workspace layout (4B units):
    float* dis     = (float*)d_ws;             // 50176
    int*   cnt     = (int*)(dis + 50176);      // 50176
    int*   row_off = cnt + 50176;              // 50432 (n+1, padded)
    int*   cursor  = row_off + 50432;          // 50176
    int*   esrc    = cursor + 50176;           // 800000
    int*   bsum    = esrc + 800000;            // 256
    int*   boff    = bsum + 256;               // 256
    float* A       = (float*)(boff + 256);     // 6.4M
    float* B       = A + (size_t)N_NODES * HIDDEN;

    // CSR build
    hipMemsetAsync(cnt, 0, 50176 * sizeof(int), stream);
    count_deg<<<(N_EDGES + 255) / 256, 256, 0, stream>>>(dst, cnt, N_EDGES);
    scan_p1<<<N_SCAN_BLKS, SCAN_BLK, 0, stream>>>(cnt, bsum, N_NODES);
    scan_p2<<<1, SCAN_BLK, 0, stream>>>(bsum, boff, N_SCAN_BLKS);
    scan_p3<<<N_SCAN_BLKS, SCAN_BLK, 0, stream>>>(cnt, boff, row_off, cursor, dis, N_NODES);
    scatter_edges<<<(N_EDGES + 255) / 256, 256, 0, stream>>>(src, dst, cursor, esrc, N_EDGES);

    const int aggGrid = (N_NODES * 64 + 255) / 256;   // one wave per node

    // Layer 1
    gemm_scale<N_FEAT><<<(N_NODES + 127) / 128, 256, 0, stream>>>(x, W1, dis, A, N_NODES);
    aggregate_csr<<<aggGrid, 256, 0, stream>>>(A, row_off, esrc, dis, b1, B, N_NODES);

    // Layer 2
    gemm_scale<HIDDEN><<<(N_NODES + 127) / 128, 256, 0, stream>>>(B, W2, dis, A, N_NODES);
    aggregate_csr<<<aggGrid, 256, 0, stream>>>(A, row_off, esrc, dis, b2, B, N_NODES);

    // Head
    head_softmax<<<(N_NODES + 255) / 256, 256, 0, stream>>>(B, Wout, bout, out, N_NODES);
}

// Round 9
// 389.957 us; speedup vs baseline: 4.0697x; 1.0183x over previous
//
#include <hip/hip_runtime.h>

// GCN 2-layer + softmax head on MI355X.
// R7 (2nd resubmit; repeated GPU-acquisition timeouts, never benched):
// (a) GEMM regeometry: BM=64 (2x grid -> ~3 blk/CU), BK=32, split-column
// microtile {4tx, 64+4tx} -> LDS-bank-minimal b-reads (R6: 3.6M conflicts,
// 13% occupancy, VALUBusy 33%); (b) aggregate processes 2 edges/wave via
// float4 lanes + shfl_xor(32) combine (halves shfl+load count, 2x MLP).

#define N_NODES 50000
#define N_EDGES 800000
#define N_FEAT 256
#define HIDDEN 128
#define N_CLASSES 16

#define SCAN_BLK 256
#define N_SCAN_BLKS ((N_NODES + SCAN_BLK - 1) / SCAN_BLK)   // 196

__device__ __forceinline__ int atomic_add_i32(int* p, int v) {
    return __hip_atomic_fetch_add(p, v, __ATOMIC_RELAXED, __HIP_MEMORY_SCOPE_AGENT);
}

// ---- CSR build ----------------------------------------------------------

__global__ void count_deg(const int* __restrict__ dst, int* __restrict__ cnt, int nE) {
    int e = blockIdx.x * blockDim.x + threadIdx.x;
    if (e < nE) atomic_add_i32(&cnt[dst[e]], 1);
}

__global__ __launch_bounds__(SCAN_BLK) void scan_p1(const int* __restrict__ cnt,
                                                    int* __restrict__ bsum, int n) {
    __shared__ int red[SCAN_BLK];
    int tid = threadIdx.x;
    int i = blockIdx.x * SCAN_BLK + tid;
    red[tid] = (i < n) ? cnt[i] : 0;
    __syncthreads();
    for (int off = SCAN_BLK / 2; off > 0; off >>= 1) {
        if (tid < off) red[tid] += red[tid + off];
        __syncthreads();
    }
    if (tid == 0) bsum[blockIdx.x] = red[0];
}

__global__ __launch_bounds__(SCAN_BLK) void scan_p2(const int* __restrict__ bsum,
                                                    int* __restrict__ boff, int nb) {
    __shared__ int s[SCAN_BLK];
    int tid = threadIdx.x;
    int v = (tid < nb) ? bsum[tid] : 0;
    s[tid] = v;
    __syncthreads();
    for (int off = 1; off < SCAN_BLK; off <<= 1) {
        int t = (tid >= off) ? s[tid - off] : 0;
        __syncthreads();
        s[tid] += t;
        __syncthreads();
    }
    boff[tid] = s[tid] - v;   // exclusive
}

__global__ __launch_bounds__(SCAN_BLK) void scan_p3(
    const int* __restrict__ cnt, const int* __restrict__ boff,
    int* __restrict__ row_off, int* __restrict__ cursor,
    float* __restrict__ dis, int n)
{
    __shared__ int s[SCAN_BLK];
    int tid = threadIdx.x;
    int i = blockIdx.x * SCAN_BLK + tid;
    int v = (i < n) ? cnt[i] : 0;
    s[tid] = v;
    __syncthreads();
    for (int off = 1; off < SCAN_BLK; off <<= 1) {
        int t = (tid >= off) ? s[tid - off] : 0;
        __syncthreads();
        s[tid] += t;
        __syncthreads();
    }
    int excl = boff[blockIdx.x] + s[tid] - v;
    if (i < n) {
        row_off[i] = excl;
        cursor[i]  = excl;
        dis[i]     = rsqrtf((float)(v + 1));   // +1 self-loop
    }
    if (blockIdx.x == 0 && tid == 0) row_off[n] = N_EDGES;
}

__global__ void scatter_edges(const int* __restrict__ src, const int* __restrict__ dst,
                              int* __restrict__ cursor, int* __restrict__ esrc, int nE)
{
    int e = blockIdx.x * blockDim.x + threadIdx.x;
    if (e < nE) {
        int pos = atomic_add_i32(&cursor[dst[e]], 1);
        esrc[pos] = src[e];
    }
}

// ---- GEMM with row-scale epilogue --------------------------------------
// C[M x 128] = (A[M x K] @ W[K x 128]) * dis[row]
// BM=64, BN=128, BK=32, 256 threads, 4x(4+4) outputs/thread.
// Thread owns rows ty*4..+3, cols {4tx..4tx+3} U {64+4tx..64+4tx+3}:
// b-read bases 4tx cover all 32 banks over tx=0..7 -> 2-cycle LDS minimum.
template <int K>
__global__ __launch_bounds__(256) void gemm_scale(
    const float* __restrict__ A, const float* __restrict__ W,
    const float* __restrict__ dis, float* __restrict__ out, int M)
{
    constexpr int BM = 64, BN = 128, BK = 32;
    __shared__ float a_lds[BK][BM + 4];   // transposed A-tile, 32x68
    __shared__ float b_lds[BK][BN];       // 32x128

    const int tid = threadIdx.x;
    const int tx = tid & 15;     // 16 column groups
    const int ty = tid >> 4;     // 16 row groups of 4
    const int row0 = blockIdx.x * BM;

    float acc[4][8] = {};

    for (int k0 = 0; k0 < K; k0 += BK) {
        // A tile: 64 rows x 32 K-cols = 512 float4, 2/thread, transposed store
#pragma unroll
        for (int p = 0; p < 2; ++p) {
            int idx = tid + p * 256;      // 0..511
            int r   = idx >> 3;           // 0..63
            int c4  = (idx & 7) * 4;      // 0,4,...,28
            int gr  = row0 + r;
            float4 v = make_float4(0.f, 0.f, 0.f, 0.f);
            if (gr < M) v = *(const float4*)(A + (size_t)gr * K + k0 + c4);
            a_lds[c4 + 0][r] = v.x;
            a_lds[c4 + 1][r] = v.y;
            a_lds[c4 + 2][r] = v.z;
            a_lds[c4 + 3][r] = v.w;
        }
        // B tile: 32 rows x 128 cols = 1024 float4, 4/thread
#pragma unroll
        for (int p = 0; p < 4; ++p) {
            int idx = tid + p * 256;
            int r   = idx >> 5;           // 0..31
            int c4  = (idx & 31) * 4;     // 0..124
            *(float4*)(&b_lds[r][c4]) = *(const float4*)(W + (size_t)(k0 + r) * BN + c4);
        }
        __syncthreads();

#pragma unroll
        for (int kk = 0; kk < BK; ++kk) {
            float a[4], b[8];
            *(float4*)(a)     = *(const float4*)(&a_lds[kk][ty * 4]);        // broadcast
            *(float4*)(b)     = *(const float4*)(&b_lds[kk][tx * 4]);        // banks 4tx
            *(float4*)(b + 4) = *(const float4*)(&b_lds[kk][64 + tx * 4]);
#pragma unroll
            for (int i = 0; i < 4; ++i)
#pragma unroll
                for (int j = 0; j < 8; ++j)
                    acc[i][j] += a[i] * b[j];
        }
        __syncthreads();
    }

#pragma unroll
    for (int i = 0; i < 4; ++i) {
        int gr = row0 + ty * 4 + i;
        if (gr < M) {
            float s = dis[gr];
            float4 o0 = make_float4(acc[i][0] * s, acc[i][1] * s, acc[i][2] * s, acc[i][3] * s);
            float4 o1 = make_float4(acc[i][4] * s, acc[i][5] * s, acc[i][6] * s, acc[i][7] * s);
            *(float4*)(out + (size_t)gr * BN + tx * 4)      = o0;
            *(float4*)(out + (size_t)gr * BN + 64 + tx * 4) = o1;
        }
    }
}

// ---- CSR aggregation, fused epilogue -----------------------------------
// One wave per destination node; 32 lanes x float4 cover the 128-wide row,
// half = lane>>5 selects which of 2 concurrent edges the lane reads.
// out[d] = relu(dis[d] * (g[d] + sum_e g[esrc[e]]) + bias)
__global__ __launch_bounds__(256) void aggregate_csr(
    const float* __restrict__ g, const int* __restrict__ row_off,
    const int* __restrict__ esrc, const float* __restrict__ dis,
    const float* __restrict__ bias, float* __restrict__ out, int M)
{
    const int wid  = (blockIdx.x * blockDim.x + threadIdx.x) >> 6;
    const int lane = threadIdx.x & 63;
    if (wid >= M) return;

    const int half = lane >> 5;        // 0 or 1: which edge of the pair
    const int col  = (lane & 31) * 4;  // float4 column

    const int beg = row_off[wid];
    const int end = row_off[wid + 1];

    float4 sum = make_float4(0.f, 0.f, 0.f, 0.f);

    for (int e0 = beg; e0 < end; e0 += 64) {
        const int cnt = min(64, end - e0);
        int myidx = (lane < cnt) ? esrc[e0 + lane] : 0;
        int j = 0;
        for (; j + 8 <= cnt; j += 8) {
            int s0 = __shfl(myidx, j + half);
            int s1 = __shfl(myidx, j + 2 + half);
            int s2 = __shfl(myidx, j + 4 + half);
            int s3 = __shfl(myidx, j + 6 + half);
            float4 v0 = *(const float4*)(g + (size_t)s0 * HIDDEN + col);
            float4 v1 = *(const float4*)(g + (size_t)s1 * HIDDEN + col);
            float4 v2 = *(const float4*)(g + (size_t)s2 * HIDDEN + col);
            float4 v3 = *(const float4*)(g + (size_t)s3 * HIDDEN + col);
            sum.x += v0.x + v1.x + v2.x + v3.x;
            sum.y += v0.y + v1.y + v2.y + v3.y;
            sum.z += v0.z + v1.z + v2.z + v3.z;
            sum.w += v0.w + v1.w + v2.w + v3.w;
        }
        for (; j + 2 <= cnt; j += 2) {
            int s = __shfl(myidx, j + half);
            float4 v = *(const float4*)(g + (size_t)s * HIDDEN + col);
            sum.x += v.x; sum.y += v.y; sum.z += v.z; sum.w += v.w;
        }
        if (j < cnt) {   // odd tail: one edge, half==0 lanes only
            int s = __shfl(myidx, j);
            if (half == 0) {
                float4 v = *(const float4*)(g + (size_t)s * HIDDEN + col);
                sum.x += v.x; sum.y += v.y; sum.z += v.z; sum.w += v.w;
            }
        }
    }

    // combine the two edge-halves (lane <-> lane^32)
    sum.x += __shfl_xor(sum.x, 32);
    sum.y += __shfl_xor(sum.y, 32);
    sum.z += __shfl_xor(sum.z, 32);
    sum.w += __shfl_xor(sum.w, 32);

    if (half == 0) {
        float4 self = *(const float4*)(g + (size_t)wid * HIDDEN + col);
        const float sc = dis[wid];
        float4 bv = *(const float4*)(bias + col);
        float4 o;
        o.x = fmaxf(sc * (sum.x + self.x) + bv.x, 0.f);
        o.y = fmaxf(sc * (sum.y + self.y) + bv.y, 0.f);
        o.z = fmaxf(sc * (sum.z + self.z) + bv.z, 0.f);
        o.w = fmaxf(sc * (sum.w + self.w) + bv.w, 0.f);
        *(float4*)(out + (size_t)wid * HIDDEN + col) = o;
    }
}

// ---- head ---------------------------------------------------------------
__global__ void head_softmax(const float* __restrict__ h, const float* __restrict__ Wout,
                             const float* __restrict__ bout, float* __restrict__ out, int M)
{
    __shared__ float w[HIDDEN * N_CLASSES];
    for (int i = threadIdx.x; i < HIDDEN * N_CLASSES; i += blockDim.x) w[i] = Wout[i];
    __syncthreads();

    int node = blockIdx.x * blockDim.x + threadIdx.x;
    if (node >= M) return;

    const float4* hp = (const float4*)(h + (size_t)node * HIDDEN);
    float acc[N_CLASSES];
#pragma unroll
    for (int c = 0; c < N_CLASSES; ++c) acc[c] = bout[c];
#pragma unroll
    for (int k4 = 0; k4 < HIDDEN / 4; ++k4) {
        float4 hv = hp[k4];
#pragma unroll
        for (int c = 0; c < N_CLASSES; ++c) {
            acc[c] += hv.x * w[(k4 * 4 + 0) * N_CLASSES + c]
                    + hv.y * w[(k4 * 4 + 1) * N_CLASSES + c]
                    + hv.z * w[(k4 * 4 + 2) * N_CLASSES + c]
                    + hv.w * w[(k4 * 4 + 3) * N_CLASSES + c];
        }
    }
    float m = acc[0];
#pragma unroll
    for (int c = 1; c < N_CLASSES; ++c) m = fmaxf(m, acc[c]);
    float sum = 0.f;
#pragma unroll
    for (int c = 0; c < N_CLASSES; ++c) { acc[c] = expf(acc[c] - m); sum += acc[c]; }
    float inv = 1.0f / sum;
#pragma unroll
    for (int c4 = 0; c4 < N_CLASSES; c4 += 4) {
        float4 o = make_float4(acc[c4] * inv, acc[c4 + 1] * inv, acc[c4 + 2] * inv, acc[c4 + 3] * inv);
        *(float4*)(out + (size_t)node * N_CLASSES + c4) = o;
    }
}

// ---- launch -------------------------------------------------------------
extern "C" void kernel_launch(void* const* d_in, const int* in_sizes, int n_in,
                              void* d_out, int out_size, void* d_ws, size_t ws_size,
                              hipStream_t stream)
{
    const float* x    = (const float*)d_in[0];
    const int*   ei   = (const int*)d_in[1];   // [2, N_EDGES]; row0=src, row1=dst
    const float* W1   = (const float*)d_in[2];
    const float* b1   = (const float*)d_in[3];
    const float* W2   = (const float*)d_in[4];
    const float* b2   = (const float*)d_in[5];
    const float* Wout = (const float*)d_in[6];
    const float* bout = (const float*)d_in[7];
    float* out = (float*)d_out;

    const int* src = ei;
    const int* dst = ei + N_EDGES;

    // Workspace layout (4B units):
    float* dis     = (float*)d_ws;             // 50176
    int*   cnt     = (int*)(dis + 50176);      // 50176
    int*   row_off = cnt + 50176;              // 50432 (n+1, padded)
    int*   cursor  = row_off + 50432;          // 50176
    int*   esrc    = cursor + 50176;           // 800000
    int*   bsum    = esrc + 800000;            // 256
    int*   boff    = bsum + 256;               // 256
    float* A       = (float*)(boff + 256);     // 6.4M
    float* B       = A + (size_t)N_NODES * HIDDEN;

    // CSR build
    hipMemsetAsync(cnt, 0, 50176 * sizeof(int), stream);
    count_deg<<<(N_EDGES + 255) / 256, 256, 0, stream>>>(dst, cnt, N_EDGES);
    scan_p1<<<N_SCAN_BLKS, SCAN_BLK, 0, stream>>>(cnt, bsum, N_NODES);
    scan_p2<<<1, SCAN_BLK, 0, stream>>>(bsum, boff, N_SCAN_BLKS);
    scan_p3<<<N_SCAN_BLKS, SCAN_BLK, 0, stream>>>(cnt, boff, row_off, cursor, dis, N_NODES);
    scatter_edges<<<(N_EDGES + 255) / 256, 256, 0, stream>>>(src, dst, cursor, esrc, N_EDGES);

    const int aggGrid = (N_NODES * 64 + 255) / 256;   // one wave per node

    // Layer 1
    gemm_scale<N_FEAT><<<(N_NODES + 63) / 64, 256, 0, stream>>>(x, W1, dis, A, N_NODES);
    aggregate_csr<<<aggGrid, 256, 0, stream>>>(A, row_off, esrc, dis, b1, B, N_NODES);

    // Layer 2
    gemm_scale<HIDDEN><<<(N_NODES + 63) / 64, 256, 0, stream>>>(B, W2, dis, A, N_NODES);
    aggregate_csr<<<aggGrid, 256, 0, stream>>>(A, row_off, esrc, dis, b2, B, N_NODES);

    // Head
    head_softmax<<<(N_NODES + 255) / 256, 256, 0, stream>>>(B, Wout, bout, out, N_NODES);
}